// Round 6
// baseline (12233.559 us; speedup 1.0000x reference)
//
#include <hip/hip_runtime.h>
#include <math.h>

#define DD 512
#define RB 16      // batch rows per block
#define NW 8       // waves per block (512 threads)

typedef _Float16 half8v __attribute__((ext_vector_type(8)));
typedef __attribute__((ext_vector_type(4))) float f32x4;

__device__ __forceinline__ float sigm(float x) { return 1.0f / (1.0f + expf(-x)); }

// Precompute gi[t][j] = (w_ih @ emb[t])[j] + b_ih[j] for both nets (fp32, tiny).
__global__ void msd_gi_kernel(const float* __restrict__ emb,
                              const float* __restrict__ wf, const float* __restrict__ bf,
                              const float* __restrict__ ws_, const float* __restrict__ bs,
                              float* __restrict__ gif, float* __restrict__ gis)
{
    int t = blockIdx.x;
    int part = blockIdx.y;          // 0..11
    int net = part / 6;             // 0 fast, 1 slow
    int j = (part % 6) * 256 + threadIdx.x;
    __shared__ float e[DD];
    for (int k = threadIdx.x; k < DD; k += 256) e[k] = emb[t * DD + k];
    __syncthreads();
    const float* w = net ? ws_ : wf;
    const float* b = net ? bs : bf;
    const float* wr = w + (size_t)j * DD;
    float acc = b[j];
    #pragma unroll 8
    for (int k = 0; k < DD; k += 4) {
        float4 wv = *reinterpret_cast<const float4*>(wr + k);
        acc = fmaf(wv.x, e[k], acc);
        acc = fmaf(wv.y, e[k + 1], acc);
        acc = fmaf(wv.z, e[k + 2], acc);
        acc = fmaf(wv.w, e[k + 3], acc);
    }
    (net ? gis : gif)[t * 1536 + j] = acc;
}

// Convert fp32 array to fp16 (vectorized x4).
__global__ void msd_f2h_kernel(const float* __restrict__ in, _Float16* __restrict__ out, int n4)
{
    int i = blockIdx.x * 256 + threadIdx.x;
    if (i >= n4) return;
    float4 v = reinterpret_cast<const float4*>(in)[i];
    _Float16 o[4] = {(_Float16)v.x, (_Float16)v.y, (_Float16)v.z, (_Float16)v.w};
    *reinterpret_cast<ushort4*>(out + (size_t)i * 4) = *reinterpret_cast<ushort4*>(o);
}

// Persistent kernel: each block owns RB=16 batch rows and runs the entire
// T-step recurrence locally. No inter-block dataflow exists (recurrence is
// batch-row-independent); states live in LDS (fp32 masters + fp16 shadows);
// weights stream from (per-XCD L2-resident) global fp16 copies.
__global__ __launch_bounds__(512, 2) void msd_persist(
    const float* __restrict__ z_init,
    const _Float16* __restrict__ wfh, const _Float16* __restrict__ wsh,
    const _Float16* __restrict__ gwh,
    const float* __restrict__ bhhF, const float* __restrict__ bhhS,
    const float* __restrict__ gi_f, const float* __restrict__ gi_s,
    const float* __restrict__ gb, const float* __restrict__ gamma,
    const float* __restrict__ beta, float* __restrict__ out, int T)
{
    __shared__ float    sZf32[RB][516];   // fast state master
    __shared__ float    sZs32[RB][516];   // slow state master
    __shared__ float    sGlog[RB][516];   // gate logits
    __shared__ _Float16 sZf16[RB][520];   // fast state fp16 (A operand)
    __shared__ _Float16 sZs16[RB][520];   // slow state fp16 (A operand)
    __shared__ _Float16 sZfn16[RB][520];  // fast GRU output fp16 (gate A operand)
    __shared__ float    sGam[DD], sBet[DD];

    const int tid = threadIdx.x;
    const int l   = tid & 63;
    const int w   = tid >> 6;        // wave 0..7
    const int lr  = l & 15;
    const int hi  = l >> 4;          // 0..3
    const int koff = hi * 8;         // fp16 elems within 32-k step
    const int er4  = hi * 4;         // D-layout row base
    const int b0   = blockIdx.x * RB;

    // ---- setup: load own rows of z_init into both states ----
    for (int i = tid; i < RB * DD; i += NW * 64) {
        int r = i >> 9, c = i & (DD - 1);
        float v = z_init[(size_t)(b0 + r) * DD + c];
        sZf32[r][c] = v; sZs32[r][c] = v;
        _Float16 h = (_Float16)v;
        sZf16[r][c] = h; sZs16[r][c] = h;
    }
    for (int c = tid; c < DD; c += NW * 64) { sGam[c] = gamma[c]; sBet[c] = beta[c]; }
    __syncthreads();

    for (int t = 0; t < T; ++t) {
        const int upd = ((t & 1) == 0);
        const float* giF = gi_f + (size_t)t * 1536;
        const float* giS = gi_s + (size_t)t * 1536;

        // ================= fast GRU =================
        {
            half8v af[16];
            #pragma unroll
            for (int kt = 0; kt < 16; ++kt)
                af[kt] = *(const half8v*)&sZf16[lr][kt * 32 + koff];

            #pragma unroll
            for (int c = 0; c < 4; ++c) {
                const int c0 = w * 64 + c * 16;
                const half8v* pR = (const half8v*)(wfh + (size_t)(c0 + lr) * DD + koff);
                const half8v* pZ = (const half8v*)(wfh + (size_t)(512 + c0 + lr) * DD + koff);
                const half8v* pN = (const half8v*)(wfh + (size_t)(1024 + c0 + lr) * DD + koff);
                f32x4 aR = {0.f,0.f,0.f,0.f}, aZ = {0.f,0.f,0.f,0.f}, aN = {0.f,0.f,0.f,0.f};
                #pragma unroll
                for (int kt = 0; kt < 16; ++kt) {
                    aR = __builtin_amdgcn_mfma_f32_16x16x32_f16(af[kt], pR[kt*4], aR, 0,0,0);
                    aZ = __builtin_amdgcn_mfma_f32_16x16x32_f16(af[kt], pZ[kt*4], aZ, 0,0,0);
                    aN = __builtin_amdgcn_mfma_f32_16x16x32_f16(af[kt], pN[kt*4], aN, 0,0,0);
                }
                const int col = c0 + lr;
                const float gir = giF[col]       + bhhF[col];
                const float giz = giF[col + 512] + bhhF[col + 512];
                const float gin = giF[col + 1024];
                const float bn  = bhhF[col + 1024];
                #pragma unroll
                for (int e = 0; e < 4; ++e) {
                    const int row = er4 + e;
                    float r_ = sigm(gir + aR[e]);
                    float zg = sigm(giz + aZ[e]);
                    float nn = tanhf(gin + r_ * (aN[e] + bn));
                    float hv = sZf32[row][col];
                    float o  = (1.f - zg) * nn + zg * hv;
                    sZfn16[row][col] = (_Float16)o;   // not read until after sync
                }
            }
        }

        // ================= slow GRU (deferred writeback) =================
        float oS[4][4];
        if (upd) {
            half8v as[16];
            #pragma unroll
            for (int kt = 0; kt < 16; ++kt)
                as[kt] = *(const half8v*)&sZs16[lr][kt * 32 + koff];

            #pragma unroll
            for (int c = 0; c < 4; ++c) {
                const int c0 = w * 64 + c * 16;
                const half8v* pR = (const half8v*)(wsh + (size_t)(c0 + lr) * DD + koff);
                const half8v* pZ = (const half8v*)(wsh + (size_t)(512 + c0 + lr) * DD + koff);
                const half8v* pN = (const half8v*)(wsh + (size_t)(1024 + c0 + lr) * DD + koff);
                f32x4 aR = {0.f,0.f,0.f,0.f}, aZ = {0.f,0.f,0.f,0.f}, aN = {0.f,0.f,0.f,0.f};
                #pragma unroll
                for (int kt = 0; kt < 16; ++kt) {
                    aR = __builtin_amdgcn_mfma_f32_16x16x32_f16(as[kt], pR[kt*4], aR, 0,0,0);
                    aZ = __builtin_amdgcn_mfma_f32_16x16x32_f16(as[kt], pZ[kt*4], aZ, 0,0,0);
                    aN = __builtin_amdgcn_mfma_f32_16x16x32_f16(as[kt], pN[kt*4], aN, 0,0,0);
                }
                const int col = c0 + lr;
                const float gir = giS[col]       + bhhS[col];
                const float giz = giS[col + 512] + bhhS[col + 512];
                const float gin = giS[col + 1024];
                const float bn  = bhhS[col + 1024];
                #pragma unroll
                for (int e = 0; e < 4; ++e) {
                    const int row = er4 + e;
                    float r_ = sigm(gir + aR[e]);
                    float zg = sigm(giz + aZ[e]);
                    float nn = tanhf(gin + r_ * (aN[e] + bn));
                    float hv = sZs32[row][col];
                    oS[c][e] = (1.f - zg) * nn + zg * hv;  // hold in regs
                }
            }
        }
        __syncthreads();                     // zfn16 complete; slow A-reads done
        if (upd) {
            #pragma unroll
            for (int c = 0; c < 4; ++c) {
                const int col = w * 64 + c * 16 + lr;
                #pragma unroll
                for (int e = 0; e < 4; ++e) {
                    const int row = er4 + e;
                    sZs32[row][col] = oS[c][e];
                    sZs16[row][col] = (_Float16)oS[c][e];
                }
            }
            __syncthreads();                 // zs16/zs32 updated for gate + next step
        }

        // ================= gate GEMM (K=1024) =================
        {
            half8v axf[16], axs[16];
            #pragma unroll
            for (int kt = 0; kt < 16; ++kt) {
                axf[kt] = *(const half8v*)&sZfn16[lr][kt * 32 + koff];
                axs[kt] = *(const half8v*)&sZs16[lr][kt * 32 + koff];
            }
            #pragma unroll
            for (int c = 0; c < 4; ++c) {
                const int c0 = w * 64 + c * 16;
                const half8v* pG = (const half8v*)(gwh + (size_t)(c0 + lr) * 1024 + koff);
                f32x4 acc = {0.f,0.f,0.f,0.f};
                #pragma unroll
                for (int kt = 0; kt < 16; ++kt)
                    acc = __builtin_amdgcn_mfma_f32_16x16x32_f16(axf[kt], pG[kt*4], acc, 0,0,0);
                #pragma unroll
                for (int kt = 0; kt < 16; ++kt)
                    acc = __builtin_amdgcn_mfma_f32_16x16x32_f16(axs[kt], pG[64 + kt*4], acc, 0,0,0);
                const int col = c0 + lr;
                const float bias = gb[col];
                #pragma unroll
                for (int e = 0; e < 4; ++e)
                    sGlog[er4 + e][col] = acc[e] + bias;
            }
        }
        __syncthreads();

        // ================= fuse + LayerNorm (2 rows per wave) =================
        #pragma unroll
        for (int rr = 0; rr < 2; ++rr) {
            const int row = w * 2 + rr;
            float p[8];
            float s = 0.f, s2 = 0.f;
            #pragma unroll
            for (int j = 0; j < 8; ++j) {
                const int c = l + j * 64;
                float g  = sigm(sGlog[row][c]);
                float pv = g * (float)sZfn16[row][c] + (1.f - g) * sZs32[row][c] + sZf32[row][c];
                p[j] = pv; s += pv; s2 += pv * pv;
            }
            #pragma unroll
            for (int off = 1; off < 64; off <<= 1) {
                s  += __shfl_xor(s, off);
                s2 += __shfl_xor(s2, off);
            }
            const float mu  = s * (1.0f / DD);
            const float inv = rsqrtf(s2 * (1.0f / DD) - mu * mu + 1e-5f);
            float* op = out + ((size_t)(b0 + row) * T + t) * DD;
            #pragma unroll
            for (int j = 0; j < 8; ++j) {
                const int c = l + j * 64;
                float o = (p[j] - mu) * inv * sGam[c] + sBet[c];
                __builtin_nontemporal_store(o, op + c);   // keep L2 for weights
                sZf32[row][c] = o;
                sZf16[row][c] = (_Float16)o;
            }
        }
        __syncthreads();   // zf16/zf32 ready for next step's fast GRU
    }
}

extern "C" void kernel_launch(void* const* d_in, const int* in_sizes, int n_in,
                              void* d_out, int out_size, void* d_ws, size_t ws_size,
                              hipStream_t stream)
{
    const float* z_init = (const float*)d_in[0];
    const float* emb    = (const float*)d_in[1];
    const float* f_wih  = (const float*)d_in[2];
    const float* f_whh  = (const float*)d_in[3];
    const float* f_bih  = (const float*)d_in[4];
    const float* f_bhh  = (const float*)d_in[5];
    const float* s_wih  = (const float*)d_in[6];
    const float* s_whh  = (const float*)d_in[7];
    const float* s_bih  = (const float*)d_in[8];
    const float* s_bhh  = (const float*)d_in[9];
    const float* gw     = (const float*)d_in[10];
    const float* gb     = (const float*)d_in[11];
    const float* gamma  = (const float*)d_in[12];
    const float* beta   = (const float*)d_in[13];

    const int B = in_sizes[0] / DD;          // 2048
    const int T = out_size / in_sizes[0];    // 64
    float* out = (float*)d_out;

    char* p = (char*)d_ws;
    auto alloc = [&](size_t bytes) { char* q = p; p += (bytes + 255) & ~(size_t)255; return q; };

    float* gi_f = (float*)alloc((size_t)T * 1536 * 4);
    float* gi_s = (float*)alloc((size_t)T * 1536 * 4);
    _Float16* wfh = (_Float16*)alloc((size_t)1536 * DD * 2);
    _Float16* wsh = (_Float16*)alloc((size_t)1536 * DD * 2);
    _Float16* gwh = (_Float16*)alloc((size_t)DD * 1024 * 2);

    msd_gi_kernel<<<dim3(T, 12), 256, 0, stream>>>(emb, f_wih, f_bih, s_wih, s_bih, gi_f, gi_s);
    msd_f2h_kernel<<<(1536 * DD / 4 + 255) / 256, 256, 0, stream>>>(f_whh, wfh, 1536 * DD / 4);
    msd_f2h_kernel<<<(1536 * DD / 4 + 255) / 256, 256, 0, stream>>>(s_whh, wsh, 1536 * DD / 4);
    msd_f2h_kernel<<<(DD * 1024 / 4 + 255) / 256, 256, 0, stream>>>(gw, gwh, DD * 1024 / 4);

    msd_persist<<<B / RB, NW * 64, 0, stream>>>(
        z_init, wfh, wsh, gwh, f_bhh, s_bhh, gi_f, gi_s, gb, gamma, beta, out, T);
}

// Round 7
// 5596.801 us; speedup vs baseline: 2.1858x; 2.1858x over previous
//
#include <hip/hip_runtime.h>
#include <math.h>

#define DD 512

typedef _Float16 half8v __attribute__((ext_vector_type(8)));
typedef __attribute__((ext_vector_type(4))) float f32x4;

__device__ __forceinline__ float sigm(float x) { return 1.0f / (1.0f + expf(-x)); }

// Precompute gi[t][j] = (w_ih @ emb[t])[j] + b_ih[j] for both nets (fp32, tiny).
__global__ void msd_gi_kernel(const float* __restrict__ emb,
                              const float* __restrict__ wf, const float* __restrict__ bf,
                              const float* __restrict__ ws_, const float* __restrict__ bs,
                              float* __restrict__ gif, float* __restrict__ gis)
{
    int t = blockIdx.x;
    int part = blockIdx.y;          // 0..11
    int net = part / 6;             // 0 fast, 1 slow
    int j = (part % 6) * 256 + threadIdx.x;
    __shared__ float e[DD];
    for (int k = threadIdx.x; k < DD; k += 256) e[k] = emb[t * DD + k];
    __syncthreads();
    const float* w = net ? ws_ : wf;
    const float* b = net ? bs : bf;
    const float* wr = w + (size_t)j * DD;
    float acc = b[j];
    #pragma unroll 8
    for (int k = 0; k < DD; k += 4) {
        float4 wv = *reinterpret_cast<const float4*>(wr + k);
        acc = fmaf(wv.x, e[k], acc);
        acc = fmaf(wv.y, e[k + 1], acc);
        acc = fmaf(wv.z, e[k + 2], acc);
        acc = fmaf(wv.w, e[k + 3], acc);
    }
    (net ? gis : gif)[t * 1536 + j] = acc;
}

// Convert fp32 array to fp16 (vectorized x4).
__global__ void msd_f2h_kernel(const float* __restrict__ in, _Float16* __restrict__ out, int n4)
{
    int i = blockIdx.x * 256 + threadIdx.x;
    if (i >= n4) return;
    float4 v = reinterpret_cast<const float4*>(in)[i];
    _Float16 o[4] = {(_Float16)v.x, (_Float16)v.y, (_Float16)v.z, (_Float16)v.w};
    *reinterpret_cast<ushort4*>(out + (size_t)i * 4) = *reinterpret_cast<ushort4*>(o);
}

__global__ void msd_init_kernel(const float* __restrict__ z, float* __restrict__ zf32,
                                float* __restrict__ zs32, _Float16* __restrict__ zf16,
                                _Float16* __restrict__ zs16, int n)
{
    int i = blockIdx.x * 256 + threadIdx.x;
    if (i < n) {
        float v = z[i];
        zf32[i] = v; zs32[i] = v;
        _Float16 h = (_Float16)v;
        zf16[i] = h; zs16[i] = h;
    }
}

// Kernel A: one GRU step. Block = 16 rows x 256 cols (8 waves, 32 cols/wave).
// grid = (2 col-halves, B/16 row-tiles, 1 + upd). z=0: fast net -> zfn16.
// z=1: slow net -> zs ping-pong out. A-fragments in registers, weights from L2.
__global__ __launch_bounds__(512, 2) void msd_gru_step(
    const _Float16* __restrict__ zf16, const _Float16* __restrict__ zs16_in,
    const float* __restrict__ zf32, const float* __restrict__ zs32_in,
    const _Float16* __restrict__ wfh, const _Float16* __restrict__ wsh,
    const float* __restrict__ bhhF, const float* __restrict__ bhhS,
    const float* __restrict__ giF, const float* __restrict__ giS,
    _Float16* __restrict__ zfn16,
    float* __restrict__ zs32_out, _Float16* __restrict__ zs16_out)
{
    const int slow = blockIdx.z;
    const _Float16* A16 = slow ? zs16_in : zf16;
    const float*    H32 = slow ? zs32_in : zf32;
    const _Float16* W   = slow ? wsh : wfh;
    const float*    bhh = slow ? bhhS : bhhF;
    const float*    gi  = slow ? giS  : giF;

    const int tid = threadIdx.x;
    const int l  = tid & 63;
    const int w  = tid >> 6;
    const int lr = l & 15;
    const int hi = l >> 4;
    const int koff = hi * 8;
    const int er4  = hi * 4;
    const int r0 = blockIdx.y * 16;
    const int c0 = blockIdx.x * 256 + w * 32;

    // A-fragments: full K=512 for 16 rows (16 half8v regs)
    half8v a[16];
    const _Float16* pA = A16 + (size_t)(r0 + lr) * DD + koff;
    #pragma unroll
    for (int kt = 0; kt < 16; ++kt)
        a[kt] = *(const half8v*)(pA + kt * 32);

    #pragma unroll
    for (int cf = 0; cf < 2; ++cf) {
        const int cc = c0 + cf * 16;
        const half8v* pR = (const half8v*)(W + (size_t)(cc + lr) * DD + koff);
        const half8v* pZ = (const half8v*)(W + (size_t)(512 + cc + lr) * DD + koff);
        const half8v* pN = (const half8v*)(W + (size_t)(1024 + cc + lr) * DD + koff);
        f32x4 aR = {0.f,0.f,0.f,0.f}, aZ = {0.f,0.f,0.f,0.f}, aN = {0.f,0.f,0.f,0.f};
        #pragma unroll
        for (int kt = 0; kt < 16; ++kt) {
            aR = __builtin_amdgcn_mfma_f32_16x16x32_f16(a[kt], pR[kt*4], aR, 0,0,0);
            aZ = __builtin_amdgcn_mfma_f32_16x16x32_f16(a[kt], pZ[kt*4], aZ, 0,0,0);
            aN = __builtin_amdgcn_mfma_f32_16x16x32_f16(a[kt], pN[kt*4], aN, 0,0,0);
        }
        const int col = cc + lr;
        const float gir = gi[col]       + bhh[col];
        const float giz = gi[col + 512] + bhh[col + 512];
        const float gin = gi[col + 1024];
        const float bn  = bhh[col + 1024];
        #pragma unroll
        for (int e = 0; e < 4; ++e) {
            const int row = r0 + er4 + e;
            float r_ = sigm(gir + aR[e]);
            float zg = sigm(giz + aZ[e]);
            float nn = tanhf(gin + r_ * (aN[e] + bn));
            float hv = H32[(size_t)row * DD + col];
            float o  = (1.f - zg) * nn + zg * hv;
            if (!slow) {
                zfn16[(size_t)row * DD + col] = (_Float16)o;
            } else {
                zs32_out[(size_t)row * DD + col] = o;
                zs16_out[(size_t)row * DD + col] = (_Float16)o;
            }
        }
    }
}

// Kernel B: gate GEMM (K=1024) + fuse + LayerNorm, fused. Block = 16 rows x
// full 512 cols (8 waves, 64 cols/wave). Writes out[t] and new zf32/zf16.
__global__ __launch_bounds__(512, 2) void msd_gate_ln(
    const _Float16* __restrict__ zfn16, const _Float16* __restrict__ zs16,
    const float* __restrict__ zs32,
    const _Float16* __restrict__ gwh, const float* __restrict__ gb,
    const float* __restrict__ gamma, const float* __restrict__ beta,
    float* __restrict__ zf32, _Float16* __restrict__ zf16,
    float* __restrict__ out, int T, int t)
{
    __shared__ float sGlog[16][516];

    const int tid = threadIdx.x;
    const int l  = tid & 63;
    const int w  = tid >> 6;
    const int lr = l & 15;
    const int hi = l >> 4;
    const int koff = hi * 8;
    const int er4  = hi * 4;
    const int r0 = blockIdx.x * 16;

    // A-fragments: zfn (K 0..512) and zs (K 512..1024)
    half8v af[16], as[16];
    {
        const _Float16* pF = zfn16 + (size_t)(r0 + lr) * DD + koff;
        const _Float16* pS = zs16  + (size_t)(r0 + lr) * DD + koff;
        #pragma unroll
        for (int kt = 0; kt < 16; ++kt) {
            af[kt] = *(const half8v*)(pF + kt * 32);
            as[kt] = *(const half8v*)(pS + kt * 32);
        }
    }

    const int c0 = w * 64;
    #pragma unroll
    for (int cf = 0; cf < 4; ++cf) {
        const int cc = c0 + cf * 16;
        const half8v* pG = (const half8v*)(gwh + (size_t)(cc + lr) * 1024 + koff);
        f32x4 acc = {0.f,0.f,0.f,0.f};
        #pragma unroll
        for (int kt = 0; kt < 16; ++kt)
            acc = __builtin_amdgcn_mfma_f32_16x16x32_f16(af[kt], pG[kt*4], acc, 0,0,0);
        #pragma unroll
        for (int kt = 0; kt < 16; ++kt)
            acc = __builtin_amdgcn_mfma_f32_16x16x32_f16(as[kt], pG[64 + kt*4], acc, 0,0,0);
        const int col = cc + lr;
        const float bias = gb[col];
        #pragma unroll
        for (int e = 0; e < 4; ++e)
            sGlog[er4 + e][col] = acc[e] + bias;
    }
    __syncthreads();

    // fuse + LN: wave w handles rows 2w, 2w+1
    #pragma unroll
    for (int rr = 0; rr < 2; ++rr) {
        const int row = w * 2 + rr;
        const size_t grow = (size_t)(r0 + row) * DD;
        float p[8];
        float s = 0.f, s2 = 0.f;
        #pragma unroll
        for (int j = 0; j < 8; ++j) {
            const int c = l + j * 64;
            float g  = sigm(sGlog[row][c]);
            float pv = g * (float)zfn16[grow + c] + (1.f - g) * zs32[grow + c] + zf32[grow + c];
            p[j] = pv; s += pv; s2 += pv * pv;
        }
        #pragma unroll
        for (int off = 1; off < 64; off <<= 1) {
            s  += __shfl_xor(s, off);
            s2 += __shfl_xor(s2, off);
        }
        const float mu  = s * (1.0f / DD);
        const float inv = rsqrtf(s2 * (1.0f / DD) - mu * mu + 1e-5f);
        float* op = out + ((size_t)(r0 + row) * T + t) * DD;
        #pragma unroll
        for (int j = 0; j < 8; ++j) {
            const int c = l + j * 64;
            float o = (p[j] - mu) * inv * gamma[c] + beta[c];
            __builtin_nontemporal_store(o, op + c);   // don't evict weights from L2
            zf32[grow + c] = o;
            zf16[grow + c] = (_Float16)o;
        }
    }
}

extern "C" void kernel_launch(void* const* d_in, const int* in_sizes, int n_in,
                              void* d_out, int out_size, void* d_ws, size_t ws_size,
                              hipStream_t stream)
{
    const float* z_init = (const float*)d_in[0];
    const float* emb    = (const float*)d_in[1];
    const float* f_wih  = (const float*)d_in[2];
    const float* f_whh  = (const float*)d_in[3];
    const float* f_bih  = (const float*)d_in[4];
    const float* f_bhh  = (const float*)d_in[5];
    const float* s_wih  = (const float*)d_in[6];
    const float* s_whh  = (const float*)d_in[7];
    const float* s_bih  = (const float*)d_in[8];
    const float* s_bhh  = (const float*)d_in[9];
    const float* gw     = (const float*)d_in[10];
    const float* gb     = (const float*)d_in[11];
    const float* gamma  = (const float*)d_in[12];
    const float* beta   = (const float*)d_in[13];

    const int B = in_sizes[0] / DD;          // 2048
    const int T = out_size / in_sizes[0];    // 64
    float* out = (float*)d_out;

    char* p = (char*)d_ws;
    auto alloc = [&](size_t bytes) { char* q = p; p += (bytes + 255) & ~(size_t)255; return q; };

    float* gi_f = (float*)alloc((size_t)T * 1536 * 4);
    float* gi_s = (float*)alloc((size_t)T * 1536 * 4);
    _Float16* wfh = (_Float16*)alloc((size_t)1536 * DD * 2);
    _Float16* wsh = (_Float16*)alloc((size_t)1536 * DD * 2);
    _Float16* gwh = (_Float16*)alloc((size_t)DD * 1024 * 2);
    size_t bd4 = (size_t)B * DD * 4;
    size_t bd2 = (size_t)B * DD * 2;
    float* zf32   = (float*)alloc(bd4);
    float* zs32a  = (float*)alloc(bd4);
    float* zs32b  = (float*)alloc(bd4);
    _Float16* zf16  = (_Float16*)alloc(bd2);
    _Float16* zs16a = (_Float16*)alloc(bd2);
    _Float16* zs16b = (_Float16*)alloc(bd2);
    _Float16* zfn16 = (_Float16*)alloc(bd2);

    msd_gi_kernel<<<dim3(T, 12), 256, 0, stream>>>(emb, f_wih, f_bih, s_wih, s_bih, gi_f, gi_s);
    msd_f2h_kernel<<<(1536 * DD / 4 + 255) / 256, 256, 0, stream>>>(f_whh, wfh, 1536 * DD / 4);
    msd_f2h_kernel<<<(1536 * DD / 4 + 255) / 256, 256, 0, stream>>>(s_whh, wsh, 1536 * DD / 4);
    msd_f2h_kernel<<<(DD * 1024 / 4 + 255) / 256, 256, 0, stream>>>(gw, gwh, DD * 1024 / 4);
    msd_init_kernel<<<(B * DD + 255) / 256, 256, 0, stream>>>(z_init, zf32, zs32a, zf16, zs16a, B * DD);

    float*    zs32c[2] = {zs32a, zs32b};
    _Float16* zs16c[2] = {zs16a, zs16b};
    int sc = 0;
    for (int t = 0; t < T; ++t) {
        const int upd = ((t & 1) == 0) ? 1 : 0;
        msd_gru_step<<<dim3(2, B / 16, 1 + upd), 512, 0, stream>>>(
            zf16, zs16c[sc], zf32, zs32c[sc], wfh, wsh, f_bhh, s_bhh,
            gi_f + (size_t)t * 1536, gi_s + (size_t)t * 1536,
            zfn16, zs32c[sc ^ 1], zs16c[sc ^ 1]);
        if (upd) sc ^= 1;
        msd_gate_ln<<<B / 16, 512, 0, stream>>>(
            zfn16, zs16c[sc], zs32c[sc], gwh, gb, gamma, beta,
            zf32, zf16, out, T, t);
    }
}